// Round 1
// baseline (103.765 us; speedup 1.0000x reference)
//
#include <hip/hip_runtime.h>

#define IMH 512
#define IMW 512
#define NP 4096
#define NBATCH 8

// Gaussian kernel, sigma = 0.3*((11-1)*0.5 - 1) + 0.8 = 2.0, normalized (f64-accurate, rounded to f32)
__device__ constexpr float KW[11] = {
    0.00881223f, 0.02714359f, 0.06511407f, 0.12164908f, 0.17699836f,
    0.20056542f, 0.17699836f, 0.12164908f, 0.06511407f, 0.02714359f, 0.00881223f};

// reflect map: valid for r in [-5, 517]; also matches the intensity pad (512->510, 513->509)
__device__ __forceinline__ int refl(int r) {
    r = r < 0 ? -r : r;
    return r > 511 ? 1022 - r : r;
}

// K1: blocks [0,1024) = dist-push partial sums; blocks [1024,3072) = vertical gaussian blur img -> ws1
__global__ __launch_bounds__(256)
void k1_dist_blur(const float* __restrict__ trace, const float* __restrict__ img,
                  float* __restrict__ ws1, float* __restrict__ accs) {
    const int tid = threadIdx.x;
    const int bx = blockIdx.x;
    if (bx < 1024) {
        // dist push: b = bx>>7, i-block = (bx>>3)&15 (256 i each), j-chunk = bx&7 (512 j each)
        __shared__ float2 pj[512];
        __shared__ float red[4];
        const int b = bx >> 7, ib = (bx >> 3) & 15, jc = bx & 7;
        const float2* tb = (const float2*)(trace + b * NP * 2);
        pj[tid] = tb[jc * 512 + tid];
        pj[tid + 256] = tb[jc * 512 + tid + 256];
        const float2 pi = tb[ib * 256 + tid];
        __syncthreads();
        float s = 0.f;
#pragma unroll 8
        for (int j = 0; j < 512; ++j) {
            float dx = pi.x - pj[j].x;
            float dy = pi.y - pj[j].y;
            float d2 = fmaf(dx, dx, dy * dy);
            // sum min(d, 0.05): max(0.05-d,0) = 0.05 - min(d,0.05), folded analytically in finalize
            s += fminf(__builtin_amdgcn_sqrtf(d2), 0.05f);
        }
        for (int o = 32; o; o >>= 1) s += __shfl_down(s, o, 64);
        if ((tid & 63) == 0) red[tid >> 6] = s;
        __syncthreads();
        if (tid == 0) atomicAdd(&accs[0], red[0] + red[1] + red[2] + red[3]);
    } else {
        // vertical blur, one float4 per thread
        const int idx = (bx - 1024) * 256 + tid;          // [0, 524288)
        const int w4 = idx & 127, h = (idx >> 7) & 511, b = idx >> 16;
        const float4* ib4 = (const float4*)(img + b * (IMH * IMW));
        float4 a = make_float4(0.f, 0.f, 0.f, 0.f);
#pragma unroll
        for (int t = 0; t < 11; ++t) {
            const int r = refl(h - 5 + t);
            const float4 v = ib4[r * 128 + w4];
            a.x = fmaf(KW[t], v.x, a.x);
            a.y = fmaf(KW[t], v.y, a.y);
            a.z = fmaf(KW[t], v.z, a.z);
            a.w = fmaf(KW[t], v.w, a.w);
        }
        ((float4*)ws1)[idx] = a;
    }
}

// K2: intensity gather (+ horizontal blur tap), block-reduce, last block finalizes output.
// LIGHT: src = vertically-blurred ws1 (24 loads/pt). !LIGHT: src = raw img, do vertical sums inline.
template <bool LIGHT>
__global__ __launch_bounds__(256)
void k2_gather(const float* __restrict__ trace, const float* __restrict__ src,
               float* __restrict__ accs, unsigned* __restrict__ cnt, float* __restrict__ out) {
    const int tid = threadIdx.x;
    const int bx = blockIdx.x;
    const int b = bx >> 4;
    const int p = (bx & 15) * 256 + tid;
    const float2 t2 = ((const float2*)trace)[b * NP + p];
    const float idx0 = t2.x * 512.f, idx1 = t2.y * 512.f;
    const float i0f = floorf(idx0 + 0.5f), j0f = floorf(idx1 + 0.5f);
    const float wi = idx0 - i0f, wj = idx1 - j0f;
    const int i0 = (int)i0f, j0 = (int)j0f;
    const int mi0 = refl(i0), mi1 = refl(i0 + 1);
    const int mj0 = refl(j0), mj1 = refl(j0 + 1);
    const int ilo = min(mi0, mi1), jlo = min(mj0, mj1);
    const bool sr = mi0 > mi1, sc = mj0 > mj1;   // window-offset flags (|mi0-mi1| == 1 always)
    const float* srcb = src + b * (IMH * IMW);

    float v0[12], v1[12];   // vertical-blurred values at rows mi0 / mi1 over the 12-col union window
    if (LIGHT) {
        const float* r0 = srcb + mi0 * IMW;
        const float* r1 = srcb + mi1 * IMW;
#pragma unroll
        for (int c = 0; c < 12; ++c) {
            const int cc = refl(jlo - 5 + c);
            v0[c] = r0[cc];
            v1[c] = r1[cc];
        }
    } else {
        int R[12];
#pragma unroll
        for (int a = 0; a < 12; ++a) R[a] = refl(ilo - 5 + a) * IMW;
#pragma unroll
        for (int c = 0; c < 12; ++c) {
            const int cc = refl(jlo - 5 + c);
            const float* col = srcb + cc;
            float lo = 0.f, hi = 0.f;
#pragma unroll
            for (int a = 0; a < 12; ++a) {
                const float pv = col[R[a]];
                if (a < 11) lo = fmaf(KW[a], pv, lo);
                if (a > 0) hi = fmaf(KW[a - 1], pv, hi);
            }
            v0[c] = sr ? hi : lo;
            v1[c] = sr ? lo : hi;
        }
    }
    float y00lo = 0.f, y00hi = 0.f, y10lo = 0.f, y10hi = 0.f;
#pragma unroll
    for (int c = 0; c < 11; ++c) {
        y00lo = fmaf(KW[c], v0[c], y00lo);
        y00hi = fmaf(KW[c], v0[c + 1], y00hi);
        y10lo = fmaf(KW[c], v1[c], y10lo);
        y10hi = fmaf(KW[c], v1[c + 1], y10hi);
    }
    const float y00 = sc ? y00hi : y00lo;
    const float y01 = sc ? y00lo : y00hi;
    const float y10 = sc ? y10hi : y10lo;
    float s = 0.5f * ((1.f - wi) * y00 + wi * y10 + (1.f - wj) * y00 + wj * y01);

    __shared__ float red[4];
    for (int o = 32; o; o >>= 1) s += __shfl_down(s, o, 64);
    if ((tid & 63) == 0) red[tid >> 6] = s;
    __syncthreads();
    if (tid == 0) {
        atomicAdd(&accs[1], red[0] + red[1] + red[2] + red[3]);
        __threadfence();
        const unsigned o = atomicAdd(cnt, 1u);
        if (o == 127u) {   // last block: finalize
            __threadfence();
            const double M = (double)atomicAdd(&accs[0], 0.f);   // sum of min(d,0.05), all ordered pairs
            const double S1 = (double)atomicAdd(&accs[1], 0.f);  // sum of intensities
            // S_full = 0.05*8*4096*4096 - M = 6710886.4 - M ; subtract self (8*4096*0.05 = 1638.4), /2, / (8*npairs)
            const double dp = (6709248.0 - M) / 134184960.0;
            const double il = 255.0 - S1 / 32768.0;
            out[0] = (float)(dp + il);
        }
    }
}

extern "C" void kernel_launch(void* const* d_in, const int* in_sizes, int n_in,
                              void* d_out, int out_size, void* d_ws, size_t ws_size,
                              hipStream_t stream) {
    const float* trace = (const float*)d_in[0];
    const float* img = (const float*)d_in[1];
    float* accs = (float*)d_ws;
    unsigned* cnt = (unsigned*)((char*)d_ws + 8);
    float* ws1 = (float*)((char*)d_ws + 64);
    float* out = (float*)d_out;
    const bool light = ws_size >= (size_t)(64 + NBATCH * IMH * IMW * 4);

    hipMemsetAsync(d_ws, 0, 64, stream);
    if (light) {
        k1_dist_blur<<<3072, 256, 0, stream>>>(trace, img, ws1, accs);
        k2_gather<true><<<128, 256, 0, stream>>>(trace, ws1, accs, cnt, out);
    } else {
        k1_dist_blur<<<1024, 256, 0, stream>>>(trace, img, ws1, accs);
        k2_gather<false><<<128, 256, 0, stream>>>(trace, img, accs, cnt, out);
    }
}